// Round 2
// baseline (1461.155 us; speedup 1.0000x reference)
//
#include <hip/hip_runtime.h>
#include <hip/hip_bf16.h>

// VariationalGCNEncoder: 4x GCNConv chain on a fixed random graph.
// Strategy: build CSR (by dst) + dinv once per launch; each layer =
// dense GEMM (bf16 W in LDS) -> gather-aggregate (wave per node, fp32 acc).
// Intermediates stored bf16 (tolerance is 2% of max|ref|).

typedef unsigned int uint;
typedef unsigned short ushort_t;

__device__ __forceinline__ float bflo(uint u) { return __uint_as_float(u << 16); }
__device__ __forceinline__ float bfhi(uint u) { return __uint_as_float(u & 0xFFFF0000u); }
__device__ __forceinline__ ushort_t f2bf(float f) {
  union { float f; uint u; } v; v.f = f;
  uint r = v.u + 0x7FFFu + ((v.u >> 16) & 1u);  // round-nearest-even
  return (ushort_t)(r >> 16);
}

// ---- CSR build ------------------------------------------------------------

__global__ void k_deg(const int* __restrict__ dst, int E, int* __restrict__ counts) {
  int idx = blockIdx.x * blockDim.x + threadIdx.x;
  if (idx < E) atomicAdd(&counts[dst[idx]], 1);
}

// Single-block exclusive scan over counts (N<=100352 with 1024 threads),
// also emits cursor copy and dinv = rsqrt(deg+1).
__global__ __launch_bounds__(1024) void k_scan(const int* __restrict__ counts,
                                               int* __restrict__ offs,
                                               int* __restrict__ cursor,
                                               float* __restrict__ dinv,
                                               int N, int E) {
  __shared__ int part[1024];
  const int t = threadIdx.x;
  const int CH = (N + 1023) >> 10;
  const int lo = t * CH;
  const int hi = min(lo + CH, N);
  int s = 0;
  for (int i = lo; i < hi; i++) s += counts[i];
  part[t] = s;
  __syncthreads();
  for (int off = 1; off < 1024; off <<= 1) {
    int u = (t >= off) ? part[t - off] : 0;
    __syncthreads();
    part[t] += u;
    __syncthreads();
  }
  int run = part[t] - s;  // exclusive base for this chunk
  for (int i = lo; i < hi; i++) {
    int ci = counts[i];
    offs[i] = run;
    cursor[i] = run;
    dinv[i] = rsqrtf((float)(ci + 1));
    run += ci;
  }
  if (t == 1023) offs[N] = E;
}

__global__ void k_fill(const int* __restrict__ src, const int* __restrict__ dst, int E,
                       int* __restrict__ cursor, int* __restrict__ csr) {
  int idx = blockIdx.x * blockDim.x + threadIdx.x;
  if (idx < E) {
    int pos = atomicAdd(&cursor[dst[idx]], 1);
    csr[pos] = src[idx];
  }
}

// ---- Dense GEMM: H[N,COUT] = X[N,CIN] @ W[CIN,COUT], bf16 out -------------
// W staged bf16-packed in LDS (<=32KB). Thread = (row, 4 consecutive cols).

template <typename TIN, int CIN, int COUT>
__global__ __launch_bounds__(256) void k_gemm(const TIN* __restrict__ X,
                                              const float* __restrict__ W,
                                              __hip_bfloat16* __restrict__ H, int N) {
  __shared__ uint Wl[CIN * COUT / 2];
  for (int idx = threadIdx.x; idx < CIN * COUT / 2; idx += 256) {
    Wl[idx] = (uint)f2bf(W[2 * idx]) | ((uint)f2bf(W[2 * idx + 1]) << 16);
  }
  __syncthreads();
  constexpr int CT = COUT / 4;   // threads per row
  constexpr int RPB = 256 / CT;  // rows per block
  const int cT = threadIdx.x % CT, rB = threadIdx.x / CT;
  const int c4 = cT * 4;
  for (int r = blockIdx.x * RPB + rB; r < N; r += gridDim.x * RPB) {
    const TIN* xr = X + (size_t)r * CIN;
    float a0 = 0, a1 = 0, a2 = 0, a3 = 0;
#pragma unroll 4
    for (int k = 0; k < CIN; k += 4) {
      float xv[4];
      if constexpr (sizeof(TIN) == 4) {
        float4 xq = *(const float4*)((const float*)xr + k);
        xv[0] = xq.x; xv[1] = xq.y; xv[2] = xq.z; xv[3] = xq.w;
      } else {
        uint2 xq = *(const uint2*)((const __hip_bfloat16*)xr + k);
        xv[0] = bflo(xq.x); xv[1] = bfhi(xq.x); xv[2] = bflo(xq.y); xv[3] = bfhi(xq.y);
      }
#pragma unroll
      for (int kk = 0; kk < 4; kk++) {
        uint2 wv = *(const uint2*)&Wl[((k + kk) * COUT + c4) >> 1];
        a0 += xv[kk] * bflo(wv.x);
        a1 += xv[kk] * bfhi(wv.x);
        a2 += xv[kk] * bflo(wv.y);
        a3 += xv[kk] * bfhi(wv.y);
      }
    }
    ushort4 o;
    o.x = f2bf(a0); o.y = f2bf(a1); o.z = f2bf(a2); o.w = f2bf(a3);
    *(ushort4*)(H + (size_t)r * COUT + c4) = o;
  }
}

// ---- Aggregation, C=128, ReLU, bf16 out (layers 1 & 3) --------------------
// Wave per node; lane owns cols (2*lane, 2*lane+1); 4-deep unrolled gather.

__global__ __launch_bounds__(256) void k_agg128(const __hip_bfloat16* __restrict__ H,
                                                const int* __restrict__ offs,
                                                const int* __restrict__ csr,
                                                const float* __restrict__ dinv,
                                                const float* __restrict__ b,
                                                __hip_bfloat16* __restrict__ OUT, int N) {
  const int lane = threadIdx.x & 63, wid = threadIdx.x >> 6;
  const int i = blockIdx.x * 4 + wid;
  if (i >= N) return;
  const int c = lane * 2;
  const float b0 = b[c], b1 = b[c + 1];
  const int beg = offs[i], end = offs[i + 1];
  float a0 = 0, a1 = 0;
  int e = beg;
  for (; e + 4 <= end; e += 4) {
    int s0 = csr[e], s1 = csr[e + 1], s2 = csr[e + 2], s3 = csr[e + 3];
    float w0 = dinv[s0], w1 = dinv[s1], w2 = dinv[s2], w3 = dinv[s3];
    uint h0 = *(const uint*)(H + (size_t)s0 * 128 + c);
    uint h1 = *(const uint*)(H + (size_t)s1 * 128 + c);
    uint h2 = *(const uint*)(H + (size_t)s2 * 128 + c);
    uint h3 = *(const uint*)(H + (size_t)s3 * 128 + c);
    a0 += w0 * bflo(h0) + w1 * bflo(h1) + w2 * bflo(h2) + w3 * bflo(h3);
    a1 += w0 * bfhi(h0) + w1 * bfhi(h1) + w2 * bfhi(h2) + w3 * bfhi(h3);
  }
  for (; e < end; e++) {
    int s = csr[e];
    float w = dinv[s];
    uint h = *(const uint*)(H + (size_t)s * 128 + c);
    a0 += w * bflo(h);
    a1 += w * bfhi(h);
  }
  const float di = dinv[i];
  uint hs = *(const uint*)(H + (size_t)i * 128 + c);
  float r0 = di * a0 + di * di * bflo(hs) + b0;
  float r1 = di * a1 + di * di * bfhi(hs) + b1;
  r0 = fmaxf(r0, 0.f);
  r1 = fmaxf(r1, 0.f);
  *(uint*)(OUT + (size_t)i * 128 + c) = (uint)f2bf(r0) | ((uint)f2bf(r1) << 16);
}

// ---- Aggregation, C=64, no ReLU, fp32 out (layers 2 & 4) ------------------
// Wave per node; half-wave per edge (2 edges in flight), lane owns 2 cols.

__global__ __launch_bounds__(256) void k_agg64(const __hip_bfloat16* __restrict__ H,
                                               const int* __restrict__ offs,
                                               const int* __restrict__ csr,
                                               const float* __restrict__ dinv,
                                               const float* __restrict__ b,
                                               float* __restrict__ OUT, int N) {
  const int lane = threadIdx.x & 63, wid = threadIdx.x >> 6;
  const int i = blockIdx.x * 4 + wid;
  if (i >= N) return;
  const int half = lane >> 5;
  const int c = (lane & 31) * 2;
  const float b0 = b[c], b1 = b[c + 1];
  const int beg = offs[i], end = offs[i + 1];
  float a0 = 0, a1 = 0;
  int e = beg + half;
  for (; e + 6 < end; e += 8) {
    int s0 = csr[e], s1 = csr[e + 2], s2 = csr[e + 4], s3 = csr[e + 6];
    float w0 = dinv[s0], w1 = dinv[s1], w2 = dinv[s2], w3 = dinv[s3];
    uint h0 = *(const uint*)(H + (size_t)s0 * 64 + c);
    uint h1 = *(const uint*)(H + (size_t)s1 * 64 + c);
    uint h2 = *(const uint*)(H + (size_t)s2 * 64 + c);
    uint h3 = *(const uint*)(H + (size_t)s3 * 64 + c);
    a0 += w0 * bflo(h0) + w1 * bflo(h1) + w2 * bflo(h2) + w3 * bflo(h3);
    a1 += w0 * bfhi(h0) + w1 * bfhi(h1) + w2 * bfhi(h2) + w3 * bfhi(h3);
  }
  for (; e < end; e += 2) {
    int s = csr[e];
    float w = dinv[s];
    uint h = *(const uint*)(H + (size_t)s * 64 + c);
    a0 += w * bflo(h);
    a1 += w * bfhi(h);
  }
  a0 += __shfl_xor(a0, 32);
  a1 += __shfl_xor(a1, 32);
  const float di = dinv[i];
  uint hs = *(const uint*)(H + (size_t)i * 64 + c);
  float r0 = di * a0 + di * di * bflo(hs) + b0;
  float r1 = di * a1 + di * di * bfhi(hs) + b1;
  if (lane < 32) *(float2*)(OUT + (size_t)i * 64 + c) = make_float2(r0, r1);
}

// ---- Launch ---------------------------------------------------------------

extern "C" void kernel_launch(void* const* d_in, const int* in_sizes, int n_in,
                              void* d_out, int out_size, void* d_ws, size_t ws_size,
                              hipStream_t stream) {
  const float* x   = (const float*)d_in[0];
  const int*   ei  = (const int*)d_in[1];
  const float* W1n = (const float*)d_in[2];
  const float* b1n = (const float*)d_in[3];
  const float* W2n = (const float*)d_in[4];
  const float* b2n = (const float*)d_in[5];
  const float* W1e = (const float*)d_in[6];
  const float* b1e = (const float*)d_in[7];
  const float* W2e = (const float*)d_in[8];
  const float* b2e = (const float*)d_in[9];
  float* out = (float*)d_out;

  const int N = in_sizes[0] / 128;  // 100000
  const int E = in_sizes[1] / 2;    // 3200000
  const int* src = ei;
  const int* dst = ei + E;

  // workspace carve (256B aligned regions), total ~65.4 MB
  char* p = (char*)d_ws;
  auto alloc = [&](size_t bytes) {
    void* q = (void*)p;
    p += (bytes + 255) & ~(size_t)255;
    return q;
  };
  int*   counts = (int*)alloc((size_t)N * 4);
  int*   offs   = (int*)alloc((size_t)(N + 1) * 4);
  int*   cursor = (int*)alloc((size_t)N * 4);
  float* dinv   = (float*)alloc((size_t)N * 4);
  int*   csr    = (int*)alloc((size_t)E * 4);
  __hip_bfloat16* hbuf = (__hip_bfloat16*)alloc((size_t)N * 128 * 2);
  __hip_bfloat16* abuf = (__hip_bfloat16*)alloc((size_t)N * 128 * 2);

  // graph structure (shared by all 4 layers)
  hipMemsetAsync(counts, 0, (size_t)N * 4, stream);
  k_deg<<<(E + 255) / 256, 256, 0, stream>>>(dst, E, counts);
  k_scan<<<1, 1024, 0, stream>>>(counts, offs, cursor, dinv, N, E);
  k_fill<<<(E + 255) / 256, 256, 0, stream>>>(src, dst, E, cursor, csr);

  // layer 1: h1 = x @ W1n ; a1 = relu(agg(h1) + b1n)
  k_gemm<float, 128, 128><<<(N + 7) / 8, 256, 0, stream>>>(x, W1n, hbuf, N);
  k_agg128<<<(N + 3) / 4, 256, 0, stream>>>(hbuf, offs, csr, dinv, b1n, abuf, N);

  // layer 2: h2 = a1 @ W2n ; mu = agg(h2) + b2n  -> d_out[0 : N*64)
  k_gemm<__hip_bfloat16, 128, 64><<<(N + 15) / 16, 256, 0, stream>>>(abuf, W2n, hbuf, N);
  k_agg64<<<(N + 3) / 4, 256, 0, stream>>>(hbuf, offs, csr, dinv, b2n, out, N);

  // layer 3: h3 = mu @ W1e ; e3 = relu(agg(h3) + b1e)
  k_gemm<float, 64, 128><<<(N + 7) / 8, 256, 0, stream>>>(out, W1e, hbuf, N);
  k_agg128<<<(N + 3) / 4, 256, 0, stream>>>(hbuf, offs, csr, dinv, b1e, abuf, N);

  // layer 4: h4 = e3 @ W2e ; logstd = agg(h4) + b2e -> d_out[N*64 : 2*N*64)
  k_gemm<__hip_bfloat16, 128, 64><<<(N + 15) / 16, 256, 0, stream>>>(abuf, W2e, hbuf, N);
  k_agg64<<<(N + 3) / 4, 256, 0, stream>>>(hbuf, offs, csr, dinv, b2e, out + (size_t)N * 64, N);
}

// Round 4
// 1119.211 us; speedup vs baseline: 1.3055x; 1.3055x over previous
//
#include <hip/hip_runtime.h>
#include <hip/hip_bf16.h>

// VariationalGCNEncoder: 4x GCNConv chain on a fixed random graph.
// CSR built via bucket binning (16 nodes/bucket): bucket histogram -> bucket
// scan -> binned (src,dst) scatter (L2-resident append windows) -> per-bucket
// LDS counting-sort emitting csr + per-node offs + dinv.
// Each layer = dense GEMM with dinv prescale (h' = dinv_r * xW, bf16) ->
// gather-aggregate: out = dinv_i*(sum h'_src + h'_i) + b.

typedef unsigned int uint;
typedef unsigned short ushort_t;

__device__ __forceinline__ float bflo(uint u) { return __uint_as_float(u << 16); }
__device__ __forceinline__ float bfhi(uint u) { return __uint_as_float(u & 0xFFFF0000u); }
__device__ __forceinline__ ushort_t f2bf(float f) {
  union { float f; uint u; } v; v.f = f;
  uint r = v.u + 0x7FFFu + ((v.u >> 16) & 1u);  // round-nearest-even
  return (ushort_t)(r >> 16);
}

#define BSH 4           // 16 nodes per bucket
#define BFCAP 1024      // LDS edge capacity per bucket (avg ~512 for this graph)

// ---- CSR build ------------------------------------------------------------

__global__ void k_bdeg(const int* __restrict__ dst, int E, int* __restrict__ bcnt) {
  int i = blockIdx.x * 256 + threadIdx.x;
  if (i < E) atomicAdd(&bcnt[dst[i] >> BSH], 1);
}

// Single-block scan over NBK (~6250) bucket counts, coalesced tiles.
__global__ __launch_bounds__(1024) void k_bscan(const int* __restrict__ bcnt,
                                                int* __restrict__ boffs,
                                                int* __restrict__ bcursor,
                                                int NBK, int E) {
  __shared__ int sc[1024];
  const int t = threadIdx.x;
  int run = 0;
  for (int base = 0; base < NBK; base += 1024) {
    int i = base + t;
    int c = (i < NBK) ? bcnt[i] : 0;
    sc[t] = c;
    __syncthreads();
    for (int off = 1; off < 1024; off <<= 1) {
      int u = (t >= off) ? sc[t - off] : 0;
      __syncthreads();
      sc[t] += u;
      __syncthreads();
    }
    int excl = sc[t] - c;
    if (i < NBK) { boffs[i] = run + excl; bcursor[i] = run + excl; }
    int total = sc[1023];
    __syncthreads();
    run += total;
  }
  if (t == 0) boffs[NBK] = E;
}

// Append (src,dst) to the dst's bucket segment. Active write window is
// ~NBK cache lines (~400KB) -> L2-resident, lines fill before eviction.
__global__ void k_binscatter(const int* __restrict__ src, const int* __restrict__ dst,
                             int E, int* __restrict__ bcursor, uint2* __restrict__ ebuf) {
  int i = blockIdx.x * 256 + threadIdx.x;
  if (i < E) {
    int d = dst[i];
    int pos = atomicAdd(&bcursor[d >> BSH], 1);
    ebuf[pos] = make_uint2((uint)src[i], (uint)d);
  }
}

// Per-bucket LDS counting sort: emits csr, per-node offs and dinv.
__global__ __launch_bounds__(256) void k_binfill(const int* __restrict__ boffs,
                                                 const uint2* __restrict__ ebuf,
                                                 int* __restrict__ csr,
                                                 int* __restrict__ offs,
                                                 float* __restrict__ dinv,
                                                 int N, int E) {
  __shared__ uint2 led[BFCAP];
  __shared__ int lcnt[16], lbase[16];
  const int b = blockIdx.x;
  const int t = threadIdx.x;
  const int lo = boffs[b], hi = boffs[b + 1];
  const int cnt = hi - lo;
  const bool inl = (cnt <= BFCAP);
  if (t < 16) lcnt[t] = 0;
  __syncthreads();
  for (int e = t; e < cnt; e += 256) {
    uint2 p = ebuf[lo + e];
    if (inl) led[e] = p;
    atomicAdd(&lcnt[p.y & 15], 1);
  }
  __syncthreads();
  if (t == 0) {
    int run = lo;
#pragma unroll
    for (int k = 0; k < 16; k++) { lbase[k] = run; run += lcnt[k]; }
  }
  __syncthreads();
  if (t < 16) {
    int node = (b << BSH) + t;
    if (node < N) {
      offs[node] = lbase[t];
      dinv[node] = rsqrtf((float)(lcnt[t] + 1));
    }
  }
  if (b == 0 && t == 16) offs[N] = E;
  if (t < 16) lcnt[t] = 0;
  __syncthreads();
  for (int e = t; e < cnt; e += 256) {
    uint2 p = inl ? led[e] : ebuf[lo + e];
    int k = (int)(p.y & 15);
    int r = atomicAdd(&lcnt[k], 1);
    csr[lbase[k] + r] = (int)p.x;
  }
}

// ---- Dense GEMM: H[r] = dinv[r] * (X[r] @ W), bf16 out --------------------
// W staged bf16-packed in LDS (<=32KB). Thread = (row, 4 consecutive cols).

template <typename TIN, int CIN, int COUT>
__global__ __launch_bounds__(256) void k_gemm(const TIN* __restrict__ X,
                                              const float* __restrict__ W,
                                              const float* __restrict__ dinv,
                                              __hip_bfloat16* __restrict__ H, int N) {
  __shared__ uint Wl[CIN * COUT / 2];
  for (int idx = threadIdx.x; idx < CIN * COUT / 2; idx += 256) {
    Wl[idx] = (uint)f2bf(W[2 * idx]) | ((uint)f2bf(W[2 * idx + 1]) << 16);
  }
  __syncthreads();
  constexpr int CT = COUT / 4;   // threads per row
  constexpr int RPB = 256 / CT;  // rows per block
  const int cT = threadIdx.x % CT, rB = threadIdx.x / CT;
  const int c4 = cT * 4;
  for (int r = blockIdx.x * RPB + rB; r < N; r += gridDim.x * RPB) {
    const TIN* xr = X + (size_t)r * CIN;
    float a0 = 0, a1 = 0, a2 = 0, a3 = 0;
#pragma unroll 4
    for (int k = 0; k < CIN; k += 4) {
      float xv[4];
      if constexpr (sizeof(TIN) == 4) {
        float4 xq = *(const float4*)((const float*)xr + k);
        xv[0] = xq.x; xv[1] = xq.y; xv[2] = xq.z; xv[3] = xq.w;
      } else {
        uint2 xq = *(const uint2*)((const __hip_bfloat16*)xr + k);
        xv[0] = bflo(xq.x); xv[1] = bfhi(xq.x); xv[2] = bflo(xq.y); xv[3] = bfhi(xq.y);
      }
#pragma unroll
      for (int kk = 0; kk < 4; kk++) {
        uint2 wv = *(const uint2*)&Wl[((k + kk) * COUT + c4) >> 1];
        a0 += xv[kk] * bflo(wv.x);
        a1 += xv[kk] * bfhi(wv.x);
        a2 += xv[kk] * bflo(wv.y);
        a3 += xv[kk] * bfhi(wv.y);
      }
    }
    const float dv = dinv[r];
    ushort4 o;
    o.x = f2bf(dv * a0); o.y = f2bf(dv * a1); o.z = f2bf(dv * a2); o.w = f2bf(dv * a3);
    *(ushort4*)(H + (size_t)r * COUT + c4) = o;
  }
}

// ---- Aggregation, C=128, ReLU, bf16 out (layers 1 & 3) --------------------
// Wave per node; lane owns cols (2*lane, 2*lane+1); 4-deep unrolled gather.
// H is pre-scaled by dinv_src, so inner loop is a pure sum.

__global__ __launch_bounds__(256) void k_agg128(const __hip_bfloat16* __restrict__ H,
                                                const int* __restrict__ offs,
                                                const int* __restrict__ csr,
                                                const float* __restrict__ dinv,
                                                const float* __restrict__ b,
                                                __hip_bfloat16* __restrict__ OUT, int N) {
  const int lane = threadIdx.x & 63, wid = threadIdx.x >> 6;
  const int i = blockIdx.x * 4 + wid;
  if (i >= N) return;
  const int c = lane * 2;
  const float b0 = b[c], b1 = b[c + 1];
  const int beg = offs[i], end = offs[i + 1];
  float a0 = 0, a1 = 0;
  int e = beg;
  for (; e + 4 <= end; e += 4) {
    int s0 = csr[e], s1 = csr[e + 1], s2 = csr[e + 2], s3 = csr[e + 3];
    uint h0 = *(const uint*)(H + (size_t)s0 * 128 + c);
    uint h1 = *(const uint*)(H + (size_t)s1 * 128 + c);
    uint h2 = *(const uint*)(H + (size_t)s2 * 128 + c);
    uint h3 = *(const uint*)(H + (size_t)s3 * 128 + c);
    a0 += bflo(h0) + bflo(h1) + bflo(h2) + bflo(h3);
    a1 += bfhi(h0) + bfhi(h1) + bfhi(h2) + bfhi(h3);
  }
  for (; e < end; e++) {
    int s = csr[e];
    uint h = *(const uint*)(H + (size_t)s * 128 + c);
    a0 += bflo(h);
    a1 += bfhi(h);
  }
  const float di = dinv[i];
  uint hs = *(const uint*)(H + (size_t)i * 128 + c);
  float r0 = di * (a0 + bflo(hs)) + b0;
  float r1 = di * (a1 + bfhi(hs)) + b1;
  r0 = fmaxf(r0, 0.f);
  r1 = fmaxf(r1, 0.f);
  *(uint*)(OUT + (size_t)i * 128 + c) = (uint)f2bf(r0) | ((uint)f2bf(r1) << 16);
}

// ---- Aggregation, C=64, no ReLU, fp32 out (layers 2 & 4) ------------------
// Wave per node; half-wave per edge (2 edges in flight), lane owns 2 cols.

__global__ __launch_bounds__(256) void k_agg64(const __hip_bfloat16* __restrict__ H,
                                               const int* __restrict__ offs,
                                               const int* __restrict__ csr,
                                               const float* __restrict__ dinv,
                                               const float* __restrict__ b,
                                               float* __restrict__ OUT, int N) {
  const int lane = threadIdx.x & 63, wid = threadIdx.x >> 6;
  const int i = blockIdx.x * 4 + wid;
  if (i >= N) return;
  const int half = lane >> 5;
  const int c = (lane & 31) * 2;
  const float b0 = b[c], b1 = b[c + 1];
  const int beg = offs[i], end = offs[i + 1];
  float a0 = 0, a1 = 0;
  int e = beg + half;
  for (; e + 6 < end; e += 8) {
    int s0 = csr[e], s1 = csr[e + 2], s2 = csr[e + 4], s3 = csr[e + 6];
    uint h0 = *(const uint*)(H + (size_t)s0 * 64 + c);
    uint h1 = *(const uint*)(H + (size_t)s1 * 64 + c);
    uint h2 = *(const uint*)(H + (size_t)s2 * 64 + c);
    uint h3 = *(const uint*)(H + (size_t)s3 * 64 + c);
    a0 += bflo(h0) + bflo(h1) + bflo(h2) + bflo(h3);
    a1 += bfhi(h0) + bfhi(h1) + bfhi(h2) + bfhi(h3);
  }
  for (; e < end; e += 2) {
    int s = csr[e];
    uint h = *(const uint*)(H + (size_t)s * 64 + c);
    a0 += bflo(h);
    a1 += bfhi(h);
  }
  a0 += __shfl_xor(a0, 32);
  a1 += __shfl_xor(a1, 32);
  const float di = dinv[i];
  uint hs = *(const uint*)(H + (size_t)i * 64 + c);
  float r0 = di * (a0 + bflo(hs)) + b0;
  float r1 = di * (a1 + bfhi(hs)) + b1;
  if (lane < 32) *(float2*)(OUT + (size_t)i * 64 + c) = make_float2(r0, r1);
}

// ---- Launch ---------------------------------------------------------------

extern "C" void kernel_launch(void* const* d_in, const int* in_sizes, int n_in,
                              void* d_out, int out_size, void* d_ws, size_t ws_size,
                              hipStream_t stream) {
  const float* x   = (const float*)d_in[0];
  const int*   ei  = (const int*)d_in[1];
  const float* W1n = (const float*)d_in[2];
  const float* b1n = (const float*)d_in[3];
  const float* W2n = (const float*)d_in[4];
  const float* b2n = (const float*)d_in[5];
  const float* W1e = (const float*)d_in[6];
  const float* b1e = (const float*)d_in[7];
  const float* W2e = (const float*)d_in[8];
  const float* b2e = (const float*)d_in[9];
  float* out = (float*)d_out;

  const int N = in_sizes[0] / 128;  // 100000
  const int E = in_sizes[1] / 2;    // 3200000
  const int NBK = (N + 15) >> BSH;  // buckets of 16 nodes
  const int* src = ei;
  const int* dst = ei + E;

  // workspace carve (256B aligned regions)
  char* p = (char*)d_ws;
  auto alloc = [&](size_t bytes) {
    void* q = (void*)p;
    p += (bytes + 255) & ~(size_t)255;
    return q;
  };
  int*   bcnt    = (int*)alloc((size_t)NBK * 4);
  int*   boffs   = (int*)alloc((size_t)(NBK + 1) * 4);
  int*   bcursor = (int*)alloc((size_t)NBK * 4);
  int*   offs    = (int*)alloc((size_t)(N + 1) * 4);
  float* dinv    = (float*)alloc((size_t)N * 4);
  int*   csr     = (int*)alloc((size_t)E * 4);
  __hip_bfloat16* hbuf = (__hip_bfloat16*)alloc((size_t)N * 128 * 2);
  __hip_bfloat16* abuf = (__hip_bfloat16*)alloc((size_t)N * 128 * 2);
  uint2* ebuf = (uint2*)hbuf;  // alias: ebuf dead before GEMM1 writes hbuf

  // graph structure (shared by all 4 layers)
  hipMemsetAsync(bcnt, 0, (size_t)NBK * 4, stream);
  k_bdeg<<<(E + 255) / 256, 256, 0, stream>>>(dst, E, bcnt);
  k_bscan<<<1, 1024, 0, stream>>>(bcnt, boffs, bcursor, NBK, E);
  k_binscatter<<<(E + 255) / 256, 256, 0, stream>>>(src, dst, E, bcursor, ebuf);
  k_binfill<<<NBK, 256, 0, stream>>>(boffs, ebuf, csr, offs, dinv, N, E);

  // layer 1: h1' = dinv*(x @ W1n) ; a1 = relu(dinv_i*(sum h1' + h1'_i) + b1n)
  k_gemm<float, 128, 128><<<(N + 7) / 8, 256, 0, stream>>>(x, W1n, dinv, hbuf, N);
  k_agg128<<<(N + 3) / 4, 256, 0, stream>>>(hbuf, offs, csr, dinv, b1n, abuf, N);

  // layer 2: mu -> d_out[0 : N*64)
  k_gemm<__hip_bfloat16, 128, 64><<<(N + 15) / 16, 256, 0, stream>>>(abuf, W2n, dinv, hbuf, N);
  k_agg64<<<(N + 3) / 4, 256, 0, stream>>>(hbuf, offs, csr, dinv, b2n, out, N);

  // layer 3
  k_gemm<float, 64, 128><<<(N + 7) / 8, 256, 0, stream>>>(out, W1e, dinv, hbuf, N);
  k_agg128<<<(N + 3) / 4, 256, 0, stream>>>(hbuf, offs, csr, dinv, b1e, abuf, N);

  // layer 4: logstd -> d_out[N*64 : 2*N*64)
  k_gemm<__hip_bfloat16, 128, 64><<<(N + 15) / 16, 256, 0, stream>>>(abuf, W2e, dinv, hbuf, N);
  k_agg64<<<(N + 3) / 4, 256, 0, stream>>>(hbuf, offs, csr, dinv, b2e, out + (size_t)N * 64, N);
}

// Round 5
// 986.400 us; speedup vs baseline: 1.4813x; 1.1346x over previous
//
#include <hip/hip_runtime.h>
#include <hip/hip_bf16.h>

// VariationalGCNEncoder: 4x GCNConv chain on a fixed random graph.
// CSR build v3: single fused scatter pass into fixed-capacity per-(bucket,
// XCD-sub) append windows (sub = blockIdx&7 ~ XCD id -> each 64B line is
// written by one XCD's L2 only, killing the 8x partial-line write
// amplification seen in round 4: WRITE_SIZE 183MB for 25.6MB of data).
// Edges packed to 4B: src (17b) | (dst&15)<<17. Then bucket-total scan +
// per-bucket LDS counting sort -> csr, offs, dinv.
// Each layer = dense GEMM with dinv prescale (h' = dinv_r * xW, bf16) ->
// gather-aggregate: out = dinv_i*(sum h'_src + h'_i) + b.

typedef unsigned int uint;
typedef unsigned short ushort_t;

__device__ __forceinline__ float bflo(uint u) { return __uint_as_float(u << 16); }
__device__ __forceinline__ float bfhi(uint u) { return __uint_as_float(u & 0xFFFF0000u); }
__device__ __forceinline__ ushort_t f2bf(float f) {
  union { float f; uint u; } v; v.f = f;
  uint r = v.u + 0x7FFFu + ((v.u >> 16) & 1u);  // round-nearest-even
  return (ushort_t)(r >> 16);
}

#define BSH 4       // 16 nodes per bucket
#define SCAP 128    // capacity per (bucket,sub) cell; load is Poisson(64), 128 = +8 sigma
#define BFCAP 1024  // LDS edge capacity per bucket (8 cells x 128)

// ---- CSR build ------------------------------------------------------------

// Fused count+scatter. Thread handles 2 edges (int2 loads). sub = blockIdx&7
// keeps each append window XCD-private under round-robin dispatch.
__global__ void k_scatter(const int* __restrict__ src, const int* __restrict__ dst,
                          int E, int* __restrict__ cnt, uint* __restrict__ ebuf) {
  int i = blockIdx.x * 256 + threadIdx.x;
  const int sub = blockIdx.x & 7;
  if (2 * i + 1 < E) {
    int2 s2 = *(const int2*)(src + 2 * i);
    int2 d2 = *(const int2*)(dst + 2 * i);
    int c0 = ((d2.x >> BSH) << 3) + sub;
    int p0 = atomicAdd(&cnt[c0], 1);
    if (p0 < SCAP) ebuf[c0 * SCAP + p0] = (uint)s2.x | ((uint)(d2.x & 15) << 17);
    int c1 = ((d2.y >> BSH) << 3) + sub;
    int p1 = atomicAdd(&cnt[c1], 1);
    if (p1 < SCAP) ebuf[c1 * SCAP + p1] = (uint)s2.y | ((uint)(d2.y & 15) << 17);
  }
}

// Exclusive scan over NBK bucket totals (sum of 8 sub-cells each).
__global__ __launch_bounds__(1024) void k_bscan(const int* __restrict__ cnt,
                                                int* __restrict__ boffs,
                                                int NBK, int E) {
  __shared__ int sc[1024];
  const int t = threadIdx.x;
  int run = 0;
  for (int base = 0; base < NBK; base += 1024) {
    int i = base + t;
    int c = 0;
    if (i < NBK) {
      const int4* q = (const int4*)(cnt + i * 8);
      int4 a = q[0], b = q[1];
      c = a.x + a.y + a.z + a.w + b.x + b.y + b.z + b.w;
    }
    sc[t] = c;
    __syncthreads();
    for (int off = 1; off < 1024; off <<= 1) {
      int u = (t >= off) ? sc[t - off] : 0;
      __syncthreads();
      sc[t] += u;
      __syncthreads();
    }
    if (i < NBK) boffs[i] = run + sc[t] - c;
    int total = sc[1023];
    __syncthreads();
    run += total;
  }
  if (t == 0) boffs[NBK] = E;
}

// Per-bucket LDS counting sort over the 8 sub-segments: emits csr, offs, dinv.
__global__ __launch_bounds__(256) void k_binfill(const int* __restrict__ cnt,
                                                 const int* __restrict__ boffs,
                                                 const uint* __restrict__ ebuf,
                                                 int* __restrict__ csr,
                                                 int* __restrict__ offs,
                                                 float* __restrict__ dinv,
                                                 int N, int E) {
  __shared__ uint led[BFCAP];
  __shared__ int lcnt[16], lbase[16], lpre[9];
  const int b = blockIdx.x;
  const int t = threadIdx.x;
  if (t < 16) lcnt[t] = 0;
  if (t == 0) {
    int r = 0;
#pragma unroll
    for (int s = 0; s < 8; s++) {
      lpre[s] = r;
      int c = cnt[b * 8 + s];
      r += (c < SCAP ? c : SCAP);
    }
    lpre[8] = r;
  }
  __syncthreads();
#pragma unroll
  for (int s = 0; s < 8; s++) {
    int base = lpre[s], len = lpre[s + 1] - base;
    for (int e = t; e < len; e += 256) led[base + e] = ebuf[(b * 8 + s) * SCAP + e];
  }
  const int total = lpre[8];
  __syncthreads();
  for (int e = t; e < total; e += 256) atomicAdd(&lcnt[(led[e] >> 17) & 15], 1);
  __syncthreads();
  if (t == 0) {
    int run = boffs[b];
#pragma unroll
    for (int k = 0; k < 16; k++) { lbase[k] = run; run += lcnt[k]; }
  }
  __syncthreads();
  if (t < 16) {
    int node = (b << BSH) + t;
    if (node < N) {
      offs[node] = lbase[t];
      dinv[node] = rsqrtf((float)(lcnt[t] + 1));
    }
  }
  if (b == 0 && t == 16) offs[N] = E;
  if (t < 16) lcnt[t] = 0;
  __syncthreads();
  for (int e = t; e < total; e += 256) {
    uint p = led[e];
    int k = (int)((p >> 17) & 15);
    int r = atomicAdd(&lcnt[k], 1);
    csr[lbase[k] + r] = (int)(p & 0x1FFFF);
  }
}

// ---- Dense GEMM: H[r] = dinv[r] * (X[r] @ W), bf16 out --------------------
// W staged bf16-packed in LDS (<=32KB). Thread = (row, 4 consecutive cols).

template <typename TIN, int CIN, int COUT>
__global__ __launch_bounds__(256) void k_gemm(const TIN* __restrict__ X,
                                              const float* __restrict__ W,
                                              const float* __restrict__ dinv,
                                              __hip_bfloat16* __restrict__ H, int N) {
  __shared__ uint Wl[CIN * COUT / 2];
  for (int idx = threadIdx.x; idx < CIN * COUT / 2; idx += 256) {
    Wl[idx] = (uint)f2bf(W[2 * idx]) | ((uint)f2bf(W[2 * idx + 1]) << 16);
  }
  __syncthreads();
  constexpr int CT = COUT / 4;   // threads per row
  constexpr int RPB = 256 / CT;  // rows per block
  const int cT = threadIdx.x % CT, rB = threadIdx.x / CT;
  const int c4 = cT * 4;
  for (int r = blockIdx.x * RPB + rB; r < N; r += gridDim.x * RPB) {
    const TIN* xr = X + (size_t)r * CIN;
    float a0 = 0, a1 = 0, a2 = 0, a3 = 0;
#pragma unroll 4
    for (int k = 0; k < CIN; k += 4) {
      float xv[4];
      if constexpr (sizeof(TIN) == 4) {
        float4 xq = *(const float4*)((const float*)xr + k);
        xv[0] = xq.x; xv[1] = xq.y; xv[2] = xq.z; xv[3] = xq.w;
      } else {
        uint2 xq = *(const uint2*)((const __hip_bfloat16*)xr + k);
        xv[0] = bflo(xq.x); xv[1] = bfhi(xq.x); xv[2] = bflo(xq.y); xv[3] = bfhi(xq.y);
      }
#pragma unroll
      for (int kk = 0; kk < 4; kk++) {
        uint2 wv = *(const uint2*)&Wl[((k + kk) * COUT + c4) >> 1];
        a0 += xv[kk] * bflo(wv.x);
        a1 += xv[kk] * bfhi(wv.x);
        a2 += xv[kk] * bflo(wv.y);
        a3 += xv[kk] * bfhi(wv.y);
      }
    }
    const float dv = dinv[r];
    ushort4 o;
    o.x = f2bf(dv * a0); o.y = f2bf(dv * a1); o.z = f2bf(dv * a2); o.w = f2bf(dv * a3);
    *(ushort4*)(H + (size_t)r * COUT + c4) = o;
  }
}

// ---- Aggregation, C=128, ReLU, bf16 out (layers 1 & 3) --------------------
// Wave per node; lane owns cols (2*lane, 2*lane+1); 4-deep unrolled gather.
// H is pre-scaled by dinv_src, so inner loop is a pure sum.

__global__ __launch_bounds__(256) void k_agg128(const __hip_bfloat16* __restrict__ H,
                                                const int* __restrict__ offs,
                                                const int* __restrict__ csr,
                                                const float* __restrict__ dinv,
                                                const float* __restrict__ b,
                                                __hip_bfloat16* __restrict__ OUT, int N) {
  const int lane = threadIdx.x & 63, wid = threadIdx.x >> 6;
  const int i = blockIdx.x * 4 + wid;
  if (i >= N) return;
  const int c = lane * 2;
  const float b0 = b[c], b1 = b[c + 1];
  const int beg = offs[i], end = offs[i + 1];
  float a0 = 0, a1 = 0;
  int e = beg;
  for (; e + 4 <= end; e += 4) {
    int s0 = csr[e], s1 = csr[e + 1], s2 = csr[e + 2], s3 = csr[e + 3];
    uint h0 = *(const uint*)(H + (size_t)s0 * 128 + c);
    uint h1 = *(const uint*)(H + (size_t)s1 * 128 + c);
    uint h2 = *(const uint*)(H + (size_t)s2 * 128 + c);
    uint h3 = *(const uint*)(H + (size_t)s3 * 128 + c);
    a0 += bflo(h0) + bflo(h1) + bflo(h2) + bflo(h3);
    a1 += bfhi(h0) + bfhi(h1) + bfhi(h2) + bfhi(h3);
  }
  for (; e < end; e++) {
    int s = csr[e];
    uint h = *(const uint*)(H + (size_t)s * 128 + c);
    a0 += bflo(h);
    a1 += bfhi(h);
  }
  const float di = dinv[i];
  uint hs = *(const uint*)(H + (size_t)i * 128 + c);
  float r0 = di * (a0 + bflo(hs)) + b0;
  float r1 = di * (a1 + bfhi(hs)) + b1;
  r0 = fmaxf(r0, 0.f);
  r1 = fmaxf(r1, 0.f);
  *(uint*)(OUT + (size_t)i * 128 + c) = (uint)f2bf(r0) | ((uint)f2bf(r1) << 16);
}

// ---- Aggregation, C=64, no ReLU, fp32 out (layers 2 & 4) ------------------
// Wave per node; half-wave per edge (2 edges in flight), lane owns 2 cols.

__global__ __launch_bounds__(256) void k_agg64(const __hip_bfloat16* __restrict__ H,
                                               const int* __restrict__ offs,
                                               const int* __restrict__ csr,
                                               const float* __restrict__ dinv,
                                               const float* __restrict__ b,
                                               float* __restrict__ OUT, int N) {
  const int lane = threadIdx.x & 63, wid = threadIdx.x >> 6;
  const int i = blockIdx.x * 4 + wid;
  if (i >= N) return;
  const int half = lane >> 5;
  const int c = (lane & 31) * 2;
  const float b0 = b[c], b1 = b[c + 1];
  const int beg = offs[i], end = offs[i + 1];
  float a0 = 0, a1 = 0;
  int e = beg + half;
  for (; e + 6 < end; e += 8) {
    int s0 = csr[e], s1 = csr[e + 2], s2 = csr[e + 4], s3 = csr[e + 6];
    uint h0 = *(const uint*)(H + (size_t)s0 * 64 + c);
    uint h1 = *(const uint*)(H + (size_t)s1 * 64 + c);
    uint h2 = *(const uint*)(H + (size_t)s2 * 64 + c);
    uint h3 = *(const uint*)(H + (size_t)s3 * 64 + c);
    a0 += bflo(h0) + bflo(h1) + bflo(h2) + bflo(h3);
    a1 += bfhi(h0) + bfhi(h1) + bfhi(h2) + bfhi(h3);
  }
  for (; e < end; e += 2) {
    int s = csr[e];
    uint h = *(const uint*)(H + (size_t)s * 64 + c);
    a0 += bflo(h);
    a1 += bfhi(h);
  }
  a0 += __shfl_xor(a0, 32);
  a1 += __shfl_xor(a1, 32);
  const float di = dinv[i];
  uint hs = *(const uint*)(H + (size_t)i * 64 + c);
  float r0 = di * (a0 + bflo(hs)) + b0;
  float r1 = di * (a1 + bfhi(hs)) + b1;
  if (lane < 32) *(float2*)(OUT + (size_t)i * 64 + c) = make_float2(r0, r1);
}

// ---- Launch ---------------------------------------------------------------

extern "C" void kernel_launch(void* const* d_in, const int* in_sizes, int n_in,
                              void* d_out, int out_size, void* d_ws, size_t ws_size,
                              hipStream_t stream) {
  const float* x   = (const float*)d_in[0];
  const int*   ei  = (const int*)d_in[1];
  const float* W1n = (const float*)d_in[2];
  const float* b1n = (const float*)d_in[3];
  const float* W2n = (const float*)d_in[4];
  const float* b2n = (const float*)d_in[5];
  const float* W1e = (const float*)d_in[6];
  const float* b1e = (const float*)d_in[7];
  const float* W2e = (const float*)d_in[8];
  const float* b2e = (const float*)d_in[9];
  float* out = (float*)d_out;

  const int N = in_sizes[0] / 128;       // 100000
  const int E = in_sizes[1] / 2;         // 3200000
  const int NBK = (N + 15) >> BSH;       // buckets of 16 nodes
  const int* src = ei;
  const int* dst = ei + E;

  // workspace carve (256B aligned regions)
  char* p = (char*)d_ws;
  auto alloc = [&](size_t bytes) {
    void* q = (void*)p;
    p += (bytes + 255) & ~(size_t)255;
    return q;
  };
  int*   cnt   = (int*)alloc((size_t)NBK * 8 * 4);      // per-(bucket,sub) counts
  int*   boffs = (int*)alloc((size_t)(NBK + 1) * 4);    // bucket csr bases
  int*   offs  = (int*)alloc((size_t)(N + 1) * 4);
  float* dinv  = (float*)alloc((size_t)N * 4);
  int*   csr   = (int*)alloc((size_t)E * 4);
  __hip_bfloat16* hbuf = (__hip_bfloat16*)alloc((size_t)N * 128 * 2);
  __hip_bfloat16* abuf = (__hip_bfloat16*)alloc((size_t)N * 128 * 2);
  uint* ebuf = (uint*)hbuf;  // alias: NBK*8*SCAP*4 = 25.6MB = hbuf size; dead before GEMM1

  // graph structure (shared by all 4 layers)
  hipMemsetAsync(cnt, 0, (size_t)NBK * 8 * 4, stream);
  k_scatter<<<(E / 2 + 255) / 256, 256, 0, stream>>>(src, dst, E, cnt, ebuf);
  k_bscan<<<1, 1024, 0, stream>>>(cnt, boffs, NBK, E);
  k_binfill<<<NBK, 256, 0, stream>>>(cnt, boffs, ebuf, csr, offs, dinv, N, E);

  // layer 1: h1' = dinv*(x @ W1n) ; a1 = relu(dinv_i*(sum h1' + h1'_i) + b1n)
  k_gemm<float, 128, 128><<<(N + 7) / 8, 256, 0, stream>>>(x, W1n, dinv, hbuf, N);
  k_agg128<<<(N + 3) / 4, 256, 0, stream>>>(hbuf, offs, csr, dinv, b1n, abuf, N);

  // layer 2: mu -> d_out[0 : N*64)
  k_gemm<__hip_bfloat16, 128, 64><<<(N + 15) / 16, 256, 0, stream>>>(abuf, W2n, dinv, hbuf, N);
  k_agg64<<<(N + 3) / 4, 256, 0, stream>>>(hbuf, offs, csr, dinv, b2n, out, N);

  // layer 3
  k_gemm<float, 64, 128><<<(N + 7) / 8, 256, 0, stream>>>(out, W1e, dinv, hbuf, N);
  k_agg128<<<(N + 3) / 4, 256, 0, stream>>>(hbuf, offs, csr, dinv, b1e, abuf, N);

  // layer 4: logstd -> d_out[N*64 : 2*N*64)
  k_gemm<__hip_bfloat16, 128, 64><<<(N + 15) / 16, 256, 0, stream>>>(abuf, W2e, dinv, hbuf, N);
  k_agg64<<<(N + 3) / 4, 256, 0, stream>>>(hbuf, offs, csr, dinv, b2e, out + (size_t)N * 64, N);
}

// Round 9
// 766.591 us; speedup vs baseline: 1.9060x; 1.2867x over previous
//
#include <hip/hip_runtime.h>
#include <hip/hip_bf16.h>

// VariationalGCNEncoder: 4x GCNConv chain on a fixed random graph.
// CSR build: fused scatter into fixed-capacity per-(bucket, XCD-sub) append
// windows (sub = blockIdx&7 -> each 64B line written by one XCD's L2; kills
// the 8x partial-line write amplification measured in round 4) -> bucket scan
// -> per-bucket LDS counting sort (csr, offs, dinv).
// Layers: MFMA GEMM (16x16x32 bf16, B-frags in registers, dinv prescale
// epilogue) -> gather-aggregate (wave per node, fp32 acc).
// All GEMM inputs bf16: k_cvt converts x once; k_agg64 emits a bf16 mirror
// of mu for layer 3. Buffer lifetimes: hbuf = ebuf -> gemm outs;
// abuf = xbf -> a1 -> mu_bf -> e3.

typedef unsigned int uint;
typedef unsigned short ushort_t;
typedef __attribute__((ext_vector_type(8))) short bf16x8;
typedef __attribute__((ext_vector_type(4))) float f32x4;

__device__ __forceinline__ float bflo(uint u) { return __uint_as_float(u << 16); }
__device__ __forceinline__ float bfhi(uint u) { return __uint_as_float(u & 0xFFFF0000u); }
__device__ __forceinline__ ushort_t f2bf(float f) {
  union { float f; uint u; } v; v.f = f;
  uint r = v.u + 0x7FFFu + ((v.u >> 16) & 1u);  // round-nearest-even
  return (ushort_t)(r >> 16);
}

#define BSH 4       // 16 nodes per bucket
#define SCAP 128    // capacity per (bucket,sub) cell; load is Poisson(64), 128 = +8 sigma
#define BFCAP 1024  // LDS edge capacity per bucket (8 cells x 128)

// ---- CSR build ------------------------------------------------------------

__global__ void k_scatter(const int* __restrict__ src, const int* __restrict__ dst,
                          int E, int* __restrict__ cnt, uint* __restrict__ ebuf) {
  int i = blockIdx.x * 256 + threadIdx.x;
  const int sub = blockIdx.x & 7;
  if (2 * i + 1 < E) {
    int2 s2 = *(const int2*)(src + 2 * i);
    int2 d2 = *(const int2*)(dst + 2 * i);
    int c0 = ((d2.x >> BSH) << 3) + sub;
    int p0 = atomicAdd(&cnt[c0], 1);
    if (p0 < SCAP) ebuf[c0 * SCAP + p0] = (uint)s2.x | ((uint)(d2.x & 15) << 17);
    int c1 = ((d2.y >> BSH) << 3) + sub;
    int p1 = atomicAdd(&cnt[c1], 1);
    if (p1 < SCAP) ebuf[c1 * SCAP + p1] = (uint)s2.y | ((uint)(d2.y & 15) << 17);
  }
}

__global__ __launch_bounds__(1024) void k_bscan(const int* __restrict__ cnt,
                                                int* __restrict__ boffs,
                                                int NBK, int E) {
  __shared__ int sc[1024];
  const int t = threadIdx.x;
  int run = 0;
  for (int base = 0; base < NBK; base += 1024) {
    int i = base + t;
    int c = 0;
    if (i < NBK) {
      const int4* q = (const int4*)(cnt + i * 8);
      int4 a = q[0], b = q[1];
      c = a.x + a.y + a.z + a.w + b.x + b.y + b.z + b.w;
    }
    sc[t] = c;
    __syncthreads();
    for (int off = 1; off < 1024; off <<= 1) {
      int u = (t >= off) ? sc[t - off] : 0;
      __syncthreads();
      sc[t] += u;
      __syncthreads();
    }
    if (i < NBK) boffs[i] = run + sc[t] - c;
    int total = sc[1023];
    __syncthreads();
    run += total;
  }
  if (t == 0) boffs[NBK] = E;
}

__global__ __launch_bounds__(256) void k_binfill(const int* __restrict__ cnt,
                                                 const int* __restrict__ boffs,
                                                 const uint* __restrict__ ebuf,
                                                 int* __restrict__ csr,
                                                 int* __restrict__ offs,
                                                 float* __restrict__ dinv,
                                                 int N, int E) {
  __shared__ uint led[BFCAP];
  __shared__ int lcnt[16], lbase[16], lpre[9];
  const int b = blockIdx.x;
  const int t = threadIdx.x;
  if (t < 16) lcnt[t] = 0;
  if (t == 0) {
    int r = 0;
#pragma unroll
    for (int s = 0; s < 8; s++) {
      lpre[s] = r;
      int c = cnt[b * 8 + s];
      r += (c < SCAP ? c : SCAP);
    }
    lpre[8] = r;
  }
  __syncthreads();
#pragma unroll
  for (int s = 0; s < 8; s++) {
    int base = lpre[s], len = lpre[s + 1] - base;
    for (int e = t; e < len; e += 256) led[base + e] = ebuf[(b * 8 + s) * SCAP + e];
  }
  const int total = lpre[8];
  __syncthreads();
  for (int e = t; e < total; e += 256) atomicAdd(&lcnt[(led[e] >> 17) & 15], 1);
  __syncthreads();
  if (t == 0) {
    int run = boffs[b];
#pragma unroll
    for (int k = 0; k < 16; k++) { lbase[k] = run; run += lcnt[k]; }
  }
  __syncthreads();
  if (t < 16) {
    int node = (b << BSH) + t;
    if (node < N) {
      offs[node] = lbase[t];
      dinv[node] = rsqrtf((float)(lcnt[t] + 1));
    }
  }
  if (b == 0 && t == 16) offs[N] = E;
  if (t < 16) lcnt[t] = 0;
  __syncthreads();
  for (int e = t; e < total; e += 256) {
    uint p = led[e];
    int k = (int)((p >> 17) & 15);
    int r = atomicAdd(&lcnt[k], 1);
    csr[lbase[k] + r] = (int)(p & 0x1FFFF);
  }
}

// ---- fp32 -> bf16 bulk convert (for x) ------------------------------------

__global__ void k_cvt(const float* __restrict__ in, uint* __restrict__ out, int n8) {
  int i = blockIdx.x * 256 + threadIdx.x;
  if (i < n8) {
    float4 a = *(const float4*)(in + 8 * i);
    float4 b = *(const float4*)(in + 8 * i + 4);
    uint4 o;
    o.x = (uint)f2bf(a.x) | ((uint)f2bf(a.y) << 16);
    o.y = (uint)f2bf(a.z) | ((uint)f2bf(a.w) << 16);
    o.z = (uint)f2bf(b.x) | ((uint)f2bf(b.y) << 16);
    o.w = (uint)f2bf(b.z) | ((uint)f2bf(b.w) << 16);
    *(uint4*)(out + 4 * i) = o;
  }
}

// ---- MFMA GEMM: H[r] = dinv[r] * (X[r] @ W), bf16 in/out ------------------
// 4 waves/block; wave owns COUT/4 cols (TPW 16-col tiles); B-frags in regs.
// Layouts (mfma_f32_16x16x32_bf16): A[row=l&15][k=(l>>4)*8+j],
// B[k=(l>>4)*8+j][col=l&15], D[row=(l>>4)*4+r][col=l&15] (m89-verified).

template <int CIN, int COUT>
__global__ __launch_bounds__(256) void k_mgemm(const __hip_bfloat16* __restrict__ X,
                                               const float* __restrict__ W,
                                               const float* __restrict__ dinv,
                                               __hip_bfloat16* __restrict__ H, int N) {
  constexpr int KCH = CIN / 32;   // k-chunks
  constexpr int TPW = COUT / 64;  // 16-col tiles per wave
  const int wid = threadIdx.x >> 6, lane = threadIdx.x & 63;
  const int l16 = lane & 15, lg = lane >> 4;
  const int cb = wid * (COUT / 4);
  bf16x8 bfr[TPW][KCH];
#pragma unroll
  for (int t = 0; t < TPW; t++) {
#pragma unroll
    for (int ch = 0; ch < KCH; ch++) {
      const int col = cb + t * 16 + l16;
      const int k0 = ch * 32 + lg * 8;
#pragma unroll
      for (int j = 0; j < 8; j++)
        bfr[t][ch][j] = (short)f2bf(W[(size_t)(k0 + j) * COUT + col]);
    }
  }
  const int RB = (N + 15) >> 4;
  for (int rb = blockIdx.x; rb < RB; rb += gridDim.x) {
    const int r0 = rb << 4;
    const int arow = min(r0 + l16, N - 1);
    const __hip_bfloat16* xr = X + (size_t)arow * CIN + lg * 8;
    bf16x8 afr[KCH];
#pragma unroll
    for (int ch = 0; ch < KCH; ch++) afr[ch] = *(const bf16x8*)(xr + ch * 32);
    f32x4 acc[TPW];
#pragma unroll
    for (int t = 0; t < TPW; t++) acc[t] = (f32x4){0.f, 0.f, 0.f, 0.f};
#pragma unroll
    for (int ch = 0; ch < KCH; ch++) {
#pragma unroll
      for (int t = 0; t < TPW; t++)
        acc[t] = __builtin_amdgcn_mfma_f32_16x16x32_bf16(afr[ch], bfr[t][ch], acc[t], 0, 0, 0);
    }
#pragma unroll
    for (int r = 0; r < 4; r++) {
      const int orow = r0 + lg * 4 + r;
      if (orow < N) {
        const float dv = dinv[orow];
#pragma unroll
        for (int t = 0; t < TPW; t++)
          *(ushort_t*)(H + (size_t)orow * COUT + cb + t * 16 + l16) = f2bf(dv * acc[t][r]);
      }
    }
  }
}

// ---- Aggregation, C=128, ReLU, bf16 out (layers 1 & 3) --------------------

__global__ __launch_bounds__(256) void k_agg128(const __hip_bfloat16* __restrict__ H,
                                                const int* __restrict__ offs,
                                                const int* __restrict__ csr,
                                                const float* __restrict__ dinv,
                                                const float* __restrict__ b,
                                                __hip_bfloat16* __restrict__ OUT, int N) {
  const int lane = threadIdx.x & 63, wid = threadIdx.x >> 6;
  const int i = blockIdx.x * 4 + wid;
  if (i >= N) return;
  const int c = lane * 2;
  const float b0 = b[c], b1 = b[c + 1];
  const int beg = offs[i], end = offs[i + 1];
  float a0 = 0, a1 = 0;
  int e = beg;
  for (; e + 4 <= end; e += 4) {
    int s0 = csr[e], s1 = csr[e + 1], s2 = csr[e + 2], s3 = csr[e + 3];
    uint h0 = *(const uint*)(H + (size_t)s0 * 128 + c);
    uint h1 = *(const uint*)(H + (size_t)s1 * 128 + c);
    uint h2 = *(const uint*)(H + (size_t)s2 * 128 + c);
    uint h3 = *(const uint*)(H + (size_t)s3 * 128 + c);
    a0 += bflo(h0) + bflo(h1) + bflo(h2) + bflo(h3);
    a1 += bfhi(h0) + bfhi(h1) + bfhi(h2) + bfhi(h3);
  }
  for (; e < end; e++) {
    int s = csr[e];
    uint h = *(const uint*)(H + (size_t)s * 128 + c);
    a0 += bflo(h);
    a1 += bfhi(h);
  }
  const float di = dinv[i];
  uint hs = *(const uint*)(H + (size_t)i * 128 + c);
  float r0 = di * (a0 + bflo(hs)) + b0;
  float r1 = di * (a1 + bfhi(hs)) + b1;
  r0 = fmaxf(r0, 0.f);
  r1 = fmaxf(r1, 0.f);
  *(uint*)(OUT + (size_t)i * 128 + c) = (uint)f2bf(r0) | ((uint)f2bf(r1) << 16);
}

// ---- Aggregation, C=64, no ReLU, fp32 out (+optional bf16 mirror) ---------

__global__ __launch_bounds__(256) void k_agg64(const __hip_bfloat16* __restrict__ H,
                                               const int* __restrict__ offs,
                                               const int* __restrict__ csr,
                                               const float* __restrict__ dinv,
                                               const float* __restrict__ b,
                                               float* __restrict__ OUT,
                                               __hip_bfloat16* __restrict__ MIR, int N) {
  const int lane = threadIdx.x & 63, wid = threadIdx.x >> 6;
  const int i = blockIdx.x * 4 + wid;
  if (i >= N) return;
  const int half = lane >> 5;
  const int c = (lane & 31) * 2;
  const float b0 = b[c], b1 = b[c + 1];
  const int beg = offs[i], end = offs[i + 1];
  float a0 = 0, a1 = 0;
  int e = beg + half;
  for (; e + 6 < end; e += 8) {
    int s0 = csr[e], s1 = csr[e + 2], s2 = csr[e + 4], s3 = csr[e + 6];
    uint h0 = *(const uint*)(H + (size_t)s0 * 64 + c);
    uint h1 = *(const uint*)(H + (size_t)s1 * 64 + c);
    uint h2 = *(const uint*)(H + (size_t)s2 * 64 + c);
    uint h3 = *(const uint*)(H + (size_t)s3 * 64 + c);
    a0 += bflo(h0) + bflo(h1) + bflo(h2) + bflo(h3);
    a1 += bfhi(h0) + bfhi(h1) + bfhi(h2) + bfhi(h3);
  }
  for (; e < end; e += 2) {
    int s = csr[e];
    uint h = *(const uint*)(H + (size_t)s * 64 + c);
    a0 += bflo(h);
    a1 += bfhi(h);
  }
  a0 += __shfl_xor(a0, 32);
  a1 += __shfl_xor(a1, 32);
  const float di = dinv[i];
  uint hs = *(const uint*)(H + (size_t)i * 64 + c);
  float r0 = di * (a0 + bflo(hs)) + b0;
  float r1 = di * (a1 + bfhi(hs)) + b1;
  if (lane < 32) {
    *(float2*)(OUT + (size_t)i * 64 + c) = make_float2(r0, r1);
    if (MIR) *(uint*)(MIR + (size_t)i * 64 + c) = (uint)f2bf(r0) | ((uint)f2bf(r1) << 16);
  }
}

// ---- Launch ---------------------------------------------------------------

extern "C" void kernel_launch(void* const* d_in, const int* in_sizes, int n_in,
                              void* d_out, int out_size, void* d_ws, size_t ws_size,
                              hipStream_t stream) {
  const float* x   = (const float*)d_in[0];
  const int*   ei  = (const int*)d_in[1];
  const float* W1n = (const float*)d_in[2];
  const float* b1n = (const float*)d_in[3];
  const float* W2n = (const float*)d_in[4];
  const float* b2n = (const float*)d_in[5];
  const float* W1e = (const float*)d_in[6];
  const float* b1e = (const float*)d_in[7];
  const float* W2e = (const float*)d_in[8];
  const float* b2e = (const float*)d_in[9];
  float* out = (float*)d_out;

  const int N = in_sizes[0] / 128;  // 100000
  const int E = in_sizes[1] / 2;    // 3200000
  const int NBK = (N + 15) >> BSH;
  const int* src = ei;
  const int* dst = ei + E;

  // workspace carve (256B aligned regions)
  char* p = (char*)d_ws;
  auto alloc = [&](size_t bytes) {
    void* q = (void*)p;
    p += (bytes + 255) & ~(size_t)255;
    return q;
  };
  int*   cnt   = (int*)alloc((size_t)NBK * 8 * 4);
  int*   boffs = (int*)alloc((size_t)(NBK + 1) * 4);
  int*   offs  = (int*)alloc((size_t)(N + 1) * 4);
  float* dinv  = (float*)alloc((size_t)N * 4);
  int*   csr   = (int*)alloc((size_t)E * 4);
  __hip_bfloat16* hbuf = (__hip_bfloat16*)alloc((size_t)N * 128 * 2);
  __hip_bfloat16* abuf = (__hip_bfloat16*)alloc((size_t)N * 128 * 2);
  uint* ebuf = (uint*)hbuf;  // CSR staging aliases hbuf (dead before GEMM1)

  const int RB = (N + 15) >> 4;
  const int GEMM_GRID = RB < 1024 ? RB : 1024;

  // graph structure (shared by all 4 layers)
  hipMemsetAsync(cnt, 0, (size_t)NBK * 8 * 4, stream);
  k_scatter<<<(E / 2 + 255) / 256, 256, 0, stream>>>(src, dst, E, cnt, ebuf);
  k_bscan<<<1, 1024, 0, stream>>>(cnt, boffs, NBK, E);
  k_binfill<<<NBK, 256, 0, stream>>>(cnt, boffs, ebuf, csr, offs, dinv, N, E);

  // x -> bf16 (abuf)
  k_cvt<<<(N * 128 / 8 + 255) / 256, 256, 0, stream>>>(x, (uint*)abuf, N * 128 / 8);

  // layer 1: h1' = dinv*(x @ W1n) ; a1 = relu(dinv_i*(sum h1' + h1'_i) + b1n)
  k_mgemm<128, 128><<<GEMM_GRID, 256, 0, stream>>>(abuf, W1n, dinv, hbuf, N);
  k_agg128<<<(N + 3) / 4, 256, 0, stream>>>(hbuf, offs, csr, dinv, b1n, abuf, N);

  // layer 2: mu -> d_out[0:N*64), bf16 mirror -> abuf
  k_mgemm<128, 64><<<GEMM_GRID, 256, 0, stream>>>(abuf, W2n, dinv, hbuf, N);
  k_agg64<<<(N + 3) / 4, 256, 0, stream>>>(hbuf, offs, csr, dinv, b2n, out, abuf, N);

  // layer 3
  k_mgemm<64, 128><<<GEMM_GRID, 256, 0, stream>>>(abuf, W1e, dinv, hbuf, N);
  k_agg128<<<(N + 3) / 4, 256, 0, stream>>>(hbuf, offs, csr, dinv, b1e, abuf, N);

  // layer 4: logstd -> d_out[N*64 : 2*N*64)
  k_mgemm<128, 64><<<GEMM_GRID, 256, 0, stream>>>(abuf, W2e, dinv, hbuf, N);
  k_agg64<<<(N + 3) / 4, 256, 0, stream>>>(hbuf, offs, csr, dinv, b2e, out + (size_t)N * 64,
                                           (__hip_bfloat16*)nullptr, N);
}